// Round 14
// baseline (686.001 us; speedup 1.0000x reference)
//
#include <hip/hip_runtime.h>
#include <hip/hip_bf16.h>
#include <math.h>

#define T_DIM 2048
#define F_DIM 513
#define N_ITER 10

// ws float offsets
#define OFF_W0   0        // 513*36*2 = 36936 (W state, parity 0)
#define OFF_W1   36936    // 36936            (W state, parity 1)
#define OFF_FLG  73872    // 10 pairs (d2,o2) per-ISS-iteration convergence sums
#define OFF_RA0  73892    // 6*2048 r2 accumulator (parity 0)
#define OFF_RA1  86180    // 6*2048 r2 accumulator (parity 1)
#define OFF_VP   98468    // 513*4*216 V partials

typedef __attribute__((ext_vector_type(8))) short bf16x8;
typedef __attribute__((ext_vector_type(4))) float f32x4;

static __device__ inline unsigned pack2bf(float a, float b) {
    union { __hip_bfloat16 h; unsigned short u; } ca, cb;
    ca.h = __float2bfloat16(a);
    cb.h = __float2bfloat16(b);
    return (unsigned)ca.u | ((unsigned)cb.u << 16);
}

// helper: expand compact value index e (0..35) into complex 6x6 (V6 = 72 floats)
static __device__ inline void scatterV(float* V6, int e, float sum) {
    if (e < 6) {
        V6[(e * 6 + e) * 2]     = sum + 1e-6f;
        V6[(e * 6 + e) * 2 + 1] = 0.f;
    } else if (e < 21) {
        int p = e - 6;
        int a = (p < 1) ? 1 : (p < 3) ? 2 : (p < 6) ? 3 : (p < 10) ? 4 : 5;
        int b = p - a * (a - 1) / 2;
        V6[(a * 6 + b) * 2] = sum;
        V6[(b * 6 + a) * 2] = sum;
    } else {
        int p = e - 21;
        int a = (p < 1) ? 1 : (p < 3) ? 2 : (p < 6) ? 3 : (p < 10) ? 4 : 5;
        int b = p - a * (a - 1) / 2;
        V6[(a * 6 + b) * 2 + 1] =  sum;
        V6[(b * 6 + a) * 2 + 1] = -sum;
    }
}

static __device__ inline bool flag_frozen(const float* flg) {
    float rel = sqrtf(flg[0]) / fmaxf(sqrtf(flg[1]), 1.1920929e-07f);
    return rel < 1e-5f;
}

// -------- transpose X (K,T,F) -> Xt (F,K,T), + init W0=I, FLG=0, RA0=0 --------
__global__ __launch_bounds__(256) void transp(const float2* __restrict__ X,
                                              float2* __restrict__ Xt,
                                              float* __restrict__ ws) {
    const int fb  = blockIdx.x + 64 * (blockIdx.y + 17 * blockIdx.z);
    const int tid = threadIdx.x;
    if (fb < 73) {
        int idx = fb * 256 + tid;
        if (idx < F_DIM * 36) {
            int e = idx % 36;
            ws[OFF_W0 + 2 * idx]     = ((e / 6) == (e % 6)) ? 1.0f : 0.0f;
            ws[OFF_W0 + 2 * idx + 1] = 0.0f;
        }
    } else if (fb == 73) {
        if (tid < 20) ws[OFF_FLG + tid] = 0.0f;
    } else if (fb < 122) {
        int idx = (fb - 74) * 256 + tid;
        if (idx < 12288) ws[OFF_RA0 + idx] = 0.0f;
    }

    __shared__ float2 tile[32][33];
    const int k  = blockIdx.z;
    const int t0 = blockIdx.x * 32;
    const int f0 = blockIdx.y * 32;
    const int tx = tid & 31, ty = tid >> 5;
#pragma unroll
    for (int j = 0; j < 4; ++j) {
        int t = t0 + ty + j * 8;
        int f = f0 + tx;
        if (f < F_DIM) tile[ty + j * 8][tx] = X[((size_t)k * T_DIM + t) * F_DIM + f];
    }
    __syncthreads();
#pragma unroll
    for (int j = 0; j < 4; ++j) {
        int f = f0 + ty + j * 8;
        int t = t0 + tx;
        if (f < F_DIM) Xt[((size_t)f * 6 + k) * T_DIM + t] = tile[tx][ty + j * 8];
    }
}

// -------- pass A1C: ISS(it-1) for 8 f's (dup x2 groups), then r2 partials --------
// grid (16 tc, 65 fc-of-8), 256 threads.
__global__ __launch_bounds__(256) void passA1C(const float2* __restrict__ Xt,
                                               float* __restrict__ ws,
                                               const float* __restrict__ flgIn,
                                               float* __restrict__ flgOut,
                                               const float* __restrict__ wOld,
                                               float* __restrict__ wNew,
                                               float* __restrict__ r2acc,
                                               int do_iss, int gate_en) {
    __shared__ float Wl[8][72];      // W rows (complex) per local f
    __shared__ float VL[8][432];     // V complex per local f; reused as r2s in body
    const int tid = threadIdx.x, wv = tid >> 6, lane = tid & 63;
    const int tc = blockIdx.x, fc = blockIdx.y;

    const bool frozen = gate_en ? flag_frozen(flgIn) : false;

    const int fl16 = wv * 4 + (lane >> 4);  // 0..15 (two duplicate groups per f)
    const int f8   = fl16 & 7;              // local f 0..7
    const int dup  = fl16 >> 3;             // 0/1 duplicate group
    const int f    = fc * 8 + f8;
    const int m    = lane & 15;             // row index (active if <6)
    const bool act = (f < F_DIM) && (m < 6);

    if (do_iss == 0) {
        if (act && dup == 0) {
            const float* Wp = wOld + ((size_t)f * 36 + m * 6) * 2;
#pragma unroll
            for (int a = 0; a < 6; ++a) {
                Wl[f8][(m * 6 + a) * 2]     = Wp[2 * a];
                Wl[f8][(m * 6 + a) * 2 + 1] = Wp[2 * a + 1];
            }
        }
    } else if (frozen) {
        if (act && dup == 0) {
            const float* Wp = wOld + ((size_t)f * 36 + m * 6) * 2;
            float* Wq = wNew + ((size_t)f * 36 + m * 6) * 2;
#pragma unroll
            for (int a = 0; a < 6; ++a) {
                float v0 = Wp[2 * a], v1 = Wp[2 * a + 1];
                Wq[2 * a] = v0; Wq[2 * a + 1] = v1;
                Wl[f8][(m * 6 + a) * 2] = v0; Wl[f8][(m * 6 + a) * 2 + 1] = v1;
            }
        }
        if (tc == 0 && m == 0 && dup == 0 && f < F_DIM) atomicAdd(&flgOut[1], 1.0f);
    } else {
        // build V (sum 4 VP partials) into VL[f8] (both dup groups write same values)
        if (f < F_DIM) {
            const float* vp = ws + OFF_VP + (size_t)f * 4 * 216;
            for (int v = m + dup * 108; v < 216; v += 16) {   // split halves across dups
                float sum = (vp[v] + vp[216 + v] + vp[432 + v] + vp[648 + v]) * (1.0f / (float)T_DIM);
                scatterV(&VL[f8][(v / 36) * 72], v % 36, sum);
            }
            // dup 0 covers v in [m, 108), dup 1 covers [108+m, 216): strides of 16 cover all
        }
        __syncthreads();
        float w6[6][2], wo6[6][2];
#pragma unroll
        for (int a = 0; a < 6; ++a) { w6[a][0] = 0.f; w6[a][1] = 0.f; wo6[a][0] = 0.f; wo6[a][1] = 0.f; }
        if (act) {
            const float* Wp = wOld + ((size_t)f * 36 + m * 6) * 2;
#pragma unroll
            for (int a = 0; a < 6; ++a) {
                w6[a][0] = Wp[2 * a]; w6[a][1] = Wp[2 * a + 1];
                wo6[a][0] = w6[a][0]; wo6[a][1] = w6[a][1];
            }
        }
        const float2* Vm = (const float2*)&VL[f8][0];
        for (int kk = 0; kk < 6; ++kk) {
            float wk[6][2];
#pragma unroll
            for (int a = 0; a < 6; ++a) {
                wk[a][0] = __shfl(w6[a][0], kk, 16);
                wk[a][1] = __shfl(w6[a][1], kk, 16);
            }
            if (act) {
                float t6[6][2];
#pragma unroll
                for (int a = 0; a < 6; ++a) {
                    float tr = 0.f, ti = 0.f;
#pragma unroll
                    for (int b = 0; b < 6; ++b) {
                        float2 vv = Vm[m * 36 + a * 6 + b];
                        tr += vv.x * wk[b][0] + vv.y * wk[b][1];
                        ti += vv.y * wk[b][0] - vv.x * wk[b][1];
                    }
                    t6[a][0] = tr; t6[a][1] = ti;
                }
                float quad = 0.f, nr = 0.f, ni = 0.f;
#pragma unroll
                for (int a = 0; a < 6; ++a) {
                    quad += wk[a][0] * t6[a][0] - wk[a][1] * t6[a][1];
                    nr   += w6[a][0] * t6[a][0] - w6[a][1] * t6[a][1];
                    ni   += w6[a][0] * t6[a][1] + w6[a][1] * t6[a][0];
                }
                float denom = fmaxf(quad, 1e-10f);
                float vkr, vki;
                if (m == kk) { vkr = 1.0f - 1.0f / sqrtf(denom); vki = 0.0f; }
                else { float inv = 1.0f / denom; vkr = nr * inv; vki = ni * inv; }
#pragma unroll
                for (int a = 0; a < 6; ++a) {
                    w6[a][0] -= vkr * wk[a][0] - vki * wk[a][1];
                    w6[a][1] -= vkr * wk[a][1] + vki * wk[a][0];
                }
            }
        }
        float d2 = 0.f, o2 = 0.f;
        if (act) {
            if (dup == 0) {
                float* Wq = wNew + ((size_t)f * 36 + m * 6) * 2;
#pragma unroll
                for (int a = 0; a < 6; ++a) {
                    Wq[2 * a] = w6[a][0]; Wq[2 * a + 1] = w6[a][1];
                    Wl[f8][(m * 6 + a) * 2] = w6[a][0]; Wl[f8][(m * 6 + a) * 2 + 1] = w6[a][1];
                }
            }
#pragma unroll
            for (int a = 0; a < 6; ++a) {
                float dr = w6[a][0] - wo6[a][0], di = w6[a][1] - wo6[a][1];
                d2 += dr * dr + di * di;
                o2 += wo6[a][0] * wo6[a][0] + wo6[a][1] * wo6[a][1];
            }
        }
#pragma unroll
        for (int d = 1; d < 8; d <<= 1) {
            d2 += __shfl_xor(d2, d);
            o2 += __shfl_xor(o2, d);
        }
        if (tc == 0 && m == 0 && dup == 0 && f < F_DIM) {
            atomicAdd(&flgOut[0], d2);
            atomicAdd(&flgOut[1], o2);
        }
    }
    __syncthreads();
    if (do_iss && frozen) return;

    // ---- body: r2 partials for the same 8 f's (2 per wave), atomic accumulate ----
    float* r2s = &VL[0][0];   // [4 wv][6 k][128 t] = 3072 floats (reuse VL)
    const int t2 = tc * 128 + lane * 2;
    float acc[6][2];
#pragma unroll
    for (int k = 0; k < 6; ++k) { acc[k][0] = 0.f; acc[k][1] = 0.f; }
#pragma unroll
    for (int i = 0; i < 2; ++i) {
        const int ff8 = wv * 2 + i;
        const int ff  = fc * 8 + ff8;
        if (ff < F_DIM) {
            const float2* xf = Xt + (size_t)ff * 6 * T_DIM;
            float4 x4[6];
#pragma unroll
            for (int mm = 0; mm < 6; ++mm)
                x4[mm] = *(const float4*)(xf + (size_t)mm * T_DIM + t2);
            const float* wrow = Wl[ff8];
#pragma unroll
            for (int k = 0; k < 6; ++k) {
                float y0r = 0.f, y0i = 0.f, y1r = 0.f, y1i = 0.f;
#pragma unroll
                for (int mm = 0; mm < 6; ++mm) {
                    float wr = wrow[(k * 6 + mm) * 2], wi = wrow[(k * 6 + mm) * 2 + 1];
                    y0r += wr * x4[mm].x - wi * x4[mm].y;
                    y0i += wr * x4[mm].y + wi * x4[mm].x;
                    y1r += wr * x4[mm].z - wi * x4[mm].w;
                    y1i += wr * x4[mm].w + wi * x4[mm].z;
                }
                acc[k][0] += y0r * y0r + y0i * y0i;
                acc[k][1] += y1r * y1r + y1i * y1i;
            }
        }
    }
    __syncthreads();   // done reading VL-as-V before overwriting as r2s
#pragma unroll
    for (int k = 0; k < 6; ++k) {
        r2s[(wv * 6 + k) * 128 + lane * 2]     = acc[k][0];
        r2s[(wv * 6 + k) * 128 + lane * 2 + 1] = acc[k][1];
    }
    __syncthreads();
    for (int v = tid; v < 768; v += 256) {
        int k = v >> 7, l = v & 127;
        float s = r2s[(0 * 6 + k) * 128 + l] + r2s[(1 * 6 + k) * 128 + l]
                + r2s[(2 * 6 + k) * 128 + l] + r2s[(3 * 6 + k) * 128 + l];
        atomicAdd(&r2acc[k * T_DIM + tc * 128 + l], s);
    }
}

// -------- pass B (MFMA): V partials per (f, t-quarter); g inline from r2 --------
__global__ __launch_bounds__(384) void passB(const float2* __restrict__ Xt,
                                             float* __restrict__ ws,
                                             const float* __restrict__ flgIn,
                                             const float* __restrict__ r2in,
                                             float* __restrict__ r2zero,
                                             int gate_en) {
    __shared__ __align__(16) char plane[16 * 528];
    __shared__ __align__(16) float gbuf[6][256];
    const int tid = threadIdx.x, wv = tid >> 6, lane = tid & 63;
    const int f = blockIdx.x, tq = blockIdx.y;

    if (gate_en && flag_frozen(flgIn)) return;

    // zero a disjoint slice of the other-parity r2 accumulator
    {
        int bb = (f * 4 + tq) * 6;
#pragma unroll
        for (int i = 0; i < 6; ++i) {
            int idx = bb + i;
            if (idx < 12288) r2zero[idx] = 0.f;
        }
    }

    const float2* xb = Xt + (size_t)f * 6 * T_DIM;

    // zero rows 12..15 once (528 dwords)
    for (int i = tid; i < 528; i += 384) ((unsigned*)(plane + 12 * 528))[i] = 0;

    f32x4 acc0 = {0.f, 0.f, 0.f, 0.f};
    f32x4 acc1 = {0.f, 0.f, 0.f, 0.f};
    const int rc = lane & 15;
    const int G  = lane >> 4;
    const char* pu = plane + rc * 528 + G * 16;
    const float* gk = &gbuf[wv][0] + G * 8;

    for (int c = 0; c < 2; ++c) {
        const int t0 = tq * 512 + c * 256;
        __syncthreads();   // prior MFMA reads done before rewrite
        for (int i = tid; i < 1536; i += 384) {
            int kk = i >> 8, toff = i & 255;
            float s = r2in[kk * T_DIM + t0 + toff];
            float r = sqrtf(fmaxf(s, 1e-10f));
            gbuf[kk][toff] = 1.0f / fmaxf(r, 1e-10f);
        }
        for (int it = tid; it < 768; it += 384) {
            int mm = it >> 7, q = it & 127;
            float4 xv = *(const float4*)(xb + (size_t)mm * T_DIM + t0 + 2 * q);
            *(unsigned*)(plane + mm * 528 + 4 * q)       = pack2bf(xv.x, xv.z);
            *(unsigned*)(plane + (6 + mm) * 528 + 4 * q) = pack2bf(xv.y, xv.w);
        }
        __syncthreads();
#pragma unroll
        for (int s = 0; s < 8; ++s) {
            bf16x8 b = *(const bf16x8*)(pu + s * 64);
            f32x4 gA = *(const f32x4*)(gk + s * 32);
            f32x4 gB = *(const f32x4*)(gk + s * 32 + 4);
            const unsigned* bu = (const unsigned*)&b;
            bf16x8 a;
            unsigned* au = (unsigned*)&a;
            au[0] = pack2bf(__uint_as_float(bu[0] << 16) * gA[0],
                            __uint_as_float(bu[0] & 0xffff0000u) * gA[1]);
            au[1] = pack2bf(__uint_as_float(bu[1] << 16) * gA[2],
                            __uint_as_float(bu[1] & 0xffff0000u) * gA[3]);
            au[2] = pack2bf(__uint_as_float(bu[2] << 16) * gB[0],
                            __uint_as_float(bu[2] & 0xffff0000u) * gB[1]);
            au[3] = pack2bf(__uint_as_float(bu[3] << 16) * gB[2],
                            __uint_as_float(bu[3] & 0xffff0000u) * gB[3]);
            if (s & 1) acc1 = __builtin_amdgcn_mfma_f32_16x16x32_bf16(a, b, acc1, 0, 0, 0);
            else       acc0 = __builtin_amdgcn_mfma_f32_16x16x32_bf16(a, b, acc0, 0, 0, 0);
        }
    }
    __syncthreads();

    // dump S_k (16x16 f32) into LDS (reuse plane region)
    float* S = (float*)plane;
    {
        float* Sk = S + wv * 256;
#pragma unroll
        for (int r = 0; r < 4; ++r)
            Sk[(4 * G + r) * 16 + rc] = acc0[r] + acc1[r];   // D: row=4G+r, col=lane&15
    }
    __syncthreads();

    if (tid < 216) {
        const int kk = tid / 36, e = tid % 36;
        const float* Sk = S + kk * 256;
        float val;
        if (e < 6) {
            val = Sk[e * 16 + e] + Sk[(6 + e) * 16 + (6 + e)];
        } else if (e < 21) {
            int p = e - 6;
            int a = (p < 1) ? 1 : (p < 3) ? 2 : (p < 6) ? 3 : (p < 10) ? 4 : 5;
            int b = p - a * (a - 1) / 2;
            val = Sk[a * 16 + b] + Sk[(6 + a) * 16 + (6 + b)];
        } else {
            int p = e - 21;
            int a = (p < 1) ? 1 : (p < 3) ? 2 : (p < 6) ? 3 : (p < 10) ? 4 : 5;
            int b = p - a * (a - 1) / 2;
            val = Sk[(6 + a) * 16 + b] - Sk[a * 16 + (6 + b)];
        }
        ws[OFF_VP + ((size_t)f * 4 + tq) * 216 + tid] = val;
    }
}

// -------- pass C (final ISS only) --------
__global__ __launch_bounds__(64) void passC(float* __restrict__ ws,
                                            const float* __restrict__ flgIn,
                                            const float* __restrict__ wOld,
                                            float* __restrict__ wNew) {
    __shared__ float VL[432];
    const int f = blockIdx.x;
    const int lane = threadIdx.x;
    if (flag_frozen(flgIn)) {
        for (int v = lane; v < 72; v += 64)
            wNew[(size_t)f * 72 + v] = wOld[(size_t)f * 72 + v];
        return;
    }
    {
        const float* vp = ws + OFF_VP + (size_t)f * 4 * 216;
        for (int v = lane; v < 216; v += 64) {
            float sum = (vp[v] + vp[216 + v] + vp[432 + v] + vp[648 + v]) * (1.0f / (float)T_DIM);
            scatterV(&VL[(v / 36) * 72], v % 36, sum);
        }
    }
    __syncthreads();

    const int m = lane;
    const bool act = (m < 6);
    float w6[6][2];
#pragma unroll
    for (int a = 0; a < 6; ++a) { w6[a][0] = 0.f; w6[a][1] = 0.f; }
    if (act) {
        const float* Wp = wOld + ((size_t)f * 36 + m * 6) * 2;
#pragma unroll
        for (int a = 0; a < 6; ++a) {
            w6[a][0] = Wp[2 * a]; w6[a][1] = Wp[2 * a + 1];
        }
    }
    const float2* Vm = (const float2*)VL;
    for (int kk = 0; kk < 6; ++kk) {
        float wk[6][2];
#pragma unroll
        for (int a = 0; a < 6; ++a) {
            wk[a][0] = __shfl(w6[a][0], kk);
            wk[a][1] = __shfl(w6[a][1], kk);
        }
        if (act) {
            float t6[6][2];
#pragma unroll
            for (int a = 0; a < 6; ++a) {
                float tr = 0.f, ti = 0.f;
#pragma unroll
                for (int b = 0; b < 6; ++b) {
                    float2 vv = Vm[m * 36 + a * 6 + b];
                    tr += vv.x * wk[b][0] + vv.y * wk[b][1];
                    ti += vv.y * wk[b][0] - vv.x * wk[b][1];
                }
                t6[a][0] = tr; t6[a][1] = ti;
            }
            float quad = 0.f, nr = 0.f, ni = 0.f;
#pragma unroll
            for (int a = 0; a < 6; ++a) {
                quad += wk[a][0] * t6[a][0] - wk[a][1] * t6[a][1];
                nr   += w6[a][0] * t6[a][0] - w6[a][1] * t6[a][1];
                ni   += w6[a][0] * t6[a][1] + w6[a][1] * t6[a][0];
            }
            float denom = fmaxf(quad, 1e-10f);
            float vkr, vki;
            if (m == kk) { vkr = 1.0f - 1.0f / sqrtf(denom); vki = 0.0f; }
            else { float inv = 1.0f / denom; vkr = nr * inv; vki = ni * inv; }
#pragma unroll
            for (int a = 0; a < 6; ++a) {
                w6[a][0] -= vkr * wk[a][0] - vki * wk[a][1];
                w6[a][1] -= vkr * wk[a][1] + vki * wk[a][0];
            }
        }
    }
    if (act) {
        float* Wq = wNew + ((size_t)f * 36 + m * 6) * 2;
#pragma unroll
        for (int a = 0; a < 6; ++a) {
            Wq[2 * a] = w6[a][0]; Wq[2 * a + 1] = w6[a][1];
        }
    }
}

// -------- final: out[k,t,f] = sum_m W[f,k,m] X[m,t,f], W cached in registers --------
__global__ __launch_bounds__(256) void finalY(const float2* __restrict__ X,
                                              const float* __restrict__ ws,
                                              float2* __restrict__ out) {
    const int f  = blockIdx.y * 256 + threadIdx.x;
    const int t0 = blockIdx.x * 4;
    if (f >= F_DIM) return;
    const float2* Wf = (const float2*)(ws + OFF_W0) + (size_t)f * 36;
    float2 w[36];
#pragma unroll
    for (int i = 0; i < 36; ++i) w[i] = Wf[i];
#pragma unroll
    for (int tl = 0; tl < 4; ++tl) {
        int t = t0 + tl;
        float2 x[6];
#pragma unroll
        for (int m = 0; m < 6; ++m) x[m] = X[((size_t)m * T_DIM + t) * F_DIM + f];
#pragma unroll
        for (int k = 0; k < 6; ++k) {
            float yr = 0.f, yi = 0.f;
#pragma unroll
            for (int m = 0; m < 6; ++m) {
                float2 wk = w[k * 6 + m];
                yr += wk.x * x[m].x - wk.y * x[m].y;
                yi += wk.x * x[m].y + wk.y * x[m].x;
            }
            out[((size_t)k * T_DIM + t) * F_DIM + f] = make_float2(yr, yi);
        }
    }
}

extern "C" void kernel_launch(void* const* d_in, const int* in_sizes, int n_in,
                              void* d_out, int out_size, void* d_ws, size_t ws_size,
                              hipStream_t stream) {
    (void)in_sizes; (void)n_in; (void)out_size; (void)ws_size;
    const float2* X = (const float2*)d_in[0];
    float* ws = (float*)d_ws;
    float2* out = (float2*)d_out;
    float2* Xt = out;  // transposed X lives in d_out until finalY overwrites it

    float* W[2]  = {ws + OFF_W0,  ws + OFF_W1};
    float* RA[2] = {ws + OFF_RA0, ws + OFF_RA1};
    float* FLG   = ws + OFF_FLG;   // FLG + 2*j = (d2,o2) sums for ISS(j)

    transp<<<dim3(64, 17, 6), 256, 0, stream>>>(X, Xt, ws);
    for (int it = 0; it < N_ITER; ++it) {
        const float* wOld = (it == 0) ? W[0] : W[(it + 1) & 1];
        float* wNew = W[it & 1];
        // A1C(it) hosts ISS(it-1): gate on FLG[it-2], write FLG[it-1]
        const float* gIn = (it >= 2) ? FLG + 2 * (it - 2) : FLG;
        float* gOut      = (it >= 1) ? FLG + 2 * (it - 1) : FLG + 18;
        passA1C<<<dim3(16, 65), 256, 0, stream>>>(Xt, ws, gIn, gOut, wOld, wNew,
                                                  RA[it & 1], it > 0, it >= 2);
        // passB(it): gate on FLG[it-1]
        const float* gB = (it >= 1) ? FLG + 2 * (it - 1) : FLG;
        passB<<<dim3(F_DIM, 4), 384, 0, stream>>>(Xt, ws, gB,
                                                  RA[it & 1], RA[(it + 1) & 1], it >= 1);
    }
    // final ISS(9): gate on FLG[8]; reads W1, writes W0
    passC<<<F_DIM, 64, 0, stream>>>(ws, FLG + 16, W[1], W[0]);
    finalY<<<dim3(T_DIM / 4, 3), 256, 0, stream>>>(X, ws, out);
}

// Round 15
// 669.915 us; speedup vs baseline: 1.0240x; 1.0240x over previous
//
#include <hip/hip_runtime.h>
#include <hip/hip_bf16.h>
#include <math.h>

#define T_DIM 2048
#define F_DIM 513
#define N_ITER 10

// ws float offsets
#define OFF_W0   0        // 513*36*2 = 36936 (W state, parity 0)
#define OFF_W1   36936    // 36936            (W state, parity 1)
#define OFF_FLG  73872    // 10 pairs (d2,o2) per-ISS-iteration sums + 2 scratch
#define OFF_RA0  73892    // 6*2048 r2 accumulator (parity 0)
#define OFF_RA1  86180    // 6*2048 r2 accumulator (parity 1)
#define OFF_VP   98468    // 513*4*216 V partials

typedef __attribute__((ext_vector_type(8))) short bf16x8;
typedef __attribute__((ext_vector_type(4))) float f32x4;

static __device__ inline unsigned pack2bf(float a, float b) {
    union { __hip_bfloat16 h; unsigned short u; } ca, cb;
    ca.h = __float2bfloat16(a);
    cb.h = __float2bfloat16(b);
    return (unsigned)ca.u | ((unsigned)cb.u << 16);
}

// helper: expand compact value index e (0..35) into complex 6x6 (V6 = 72 floats)
static __device__ inline void scatterV(float* V6, int e, float sum) {
    if (e < 6) {
        V6[(e * 6 + e) * 2]     = sum + 1e-6f;
        V6[(e * 6 + e) * 2 + 1] = 0.f;
    } else if (e < 21) {
        int p = e - 6;
        int a = (p < 1) ? 1 : (p < 3) ? 2 : (p < 6) ? 3 : (p < 10) ? 4 : 5;
        int b = p - a * (a - 1) / 2;
        V6[(a * 6 + b) * 2] = sum;
        V6[(b * 6 + a) * 2] = sum;
    } else {
        int p = e - 21;
        int a = (p < 1) ? 1 : (p < 3) ? 2 : (p < 6) ? 3 : (p < 10) ? 4 : 5;
        int b = p - a * (a - 1) / 2;
        V6[(a * 6 + b) * 2 + 1] =  sum;
        V6[(b * 6 + a) * 2 + 1] = -sum;
    }
}

static __device__ inline bool flag_frozen(const float* flg) {
    float rel = sqrtf(flg[0]) / fmaxf(sqrtf(flg[1]), 1.1920929e-07f);
    return rel < 1e-5f;
}

// -------- transpose X (K,T,F) -> Xt (F,K,T), + init W0=I, FLG=0, RA0=0 --------
__global__ __launch_bounds__(256) void transp(const float2* __restrict__ X,
                                              float2* __restrict__ Xt,
                                              float* __restrict__ ws) {
    const int fb  = blockIdx.x + 64 * (blockIdx.y + 17 * blockIdx.z);
    const int tid = threadIdx.x;
    if (fb < 73) {
        int idx = fb * 256 + tid;
        if (idx < F_DIM * 36) {
            int e = idx % 36;
            ws[OFF_W0 + 2 * idx]     = ((e / 6) == (e % 6)) ? 1.0f : 0.0f;
            ws[OFF_W0 + 2 * idx + 1] = 0.0f;
        }
    } else if (fb == 73) {
        if (tid < 20) ws[OFF_FLG + tid] = 0.0f;
    } else if (fb < 122) {
        int idx = (fb - 74) * 256 + tid;
        if (idx < 12288) ws[OFF_RA0 + idx] = 0.0f;
    }

    __shared__ float2 tile[32][33];
    const int k  = blockIdx.z;
    const int t0 = blockIdx.x * 32;
    const int f0 = blockIdx.y * 32;
    const int tx = tid & 31, ty = tid >> 5;
#pragma unroll
    for (int j = 0; j < 4; ++j) {
        int t = t0 + ty + j * 8;
        int f = f0 + tx;
        if (f < F_DIM) tile[ty + j * 8][tx] = X[((size_t)k * T_DIM + t) * F_DIM + f];
    }
    __syncthreads();
#pragma unroll
    for (int j = 0; j < 4; ++j) {
        int f = f0 + ty + j * 8;
        int t = t0 + tx;
        if (f < F_DIM) Xt[((size_t)f * 6 + k) * T_DIM + t] = tile[tx][ty + j * 8];
    }
}

// -------- pass I: ISS update for one f (V from VP partials), flag atomics --------
__global__ __launch_bounds__(64) void passI(float* __restrict__ ws,
                                            const float* __restrict__ flgIn,
                                            float* __restrict__ flgOut,
                                            const float* __restrict__ wOld,
                                            float* __restrict__ wNew,
                                            int gate_en) {
    __shared__ float VL[432];
    const int f = blockIdx.x;
    const int lane = threadIdx.x;
    if (gate_en && flag_frozen(flgIn)) {
        for (int v = lane; v < 72; v += 64)
            wNew[(size_t)f * 72 + v] = wOld[(size_t)f * 72 + v];
        if (lane == 0) atomicAdd(&flgOut[1], 1.0f);
        return;
    }
    {
        const float* vp = ws + OFF_VP + (size_t)f * 4 * 216;
        for (int v = lane; v < 216; v += 64) {
            float sum = (vp[v] + vp[216 + v] + vp[432 + v] + vp[648 + v]) * (1.0f / (float)T_DIM);
            scatterV(&VL[(v / 36) * 72], v % 36, sum);
        }
    }
    __syncthreads();

    const int m = lane;
    const bool act = (m < 6);
    float w6[6][2], wo6[6][2];
#pragma unroll
    for (int a = 0; a < 6; ++a) { w6[a][0] = 0.f; w6[a][1] = 0.f; wo6[a][0] = 0.f; wo6[a][1] = 0.f; }
    if (act) {
        const float* Wp = wOld + ((size_t)f * 36 + m * 6) * 2;
#pragma unroll
        for (int a = 0; a < 6; ++a) {
            w6[a][0] = Wp[2 * a]; w6[a][1] = Wp[2 * a + 1];
            wo6[a][0] = w6[a][0]; wo6[a][1] = w6[a][1];
        }
    }
    const float2* Vm = (const float2*)VL;
    for (int kk = 0; kk < 6; ++kk) {
        float wk[6][2];
#pragma unroll
        for (int a = 0; a < 6; ++a) {
            wk[a][0] = __shfl(w6[a][0], kk);
            wk[a][1] = __shfl(w6[a][1], kk);
        }
        if (act) {
            float t6[6][2];
#pragma unroll
            for (int a = 0; a < 6; ++a) {
                float tr = 0.f, ti = 0.f;
#pragma unroll
                for (int b = 0; b < 6; ++b) {
                    float2 vv = Vm[m * 36 + a * 6 + b];
                    tr += vv.x * wk[b][0] + vv.y * wk[b][1];
                    ti += vv.y * wk[b][0] - vv.x * wk[b][1];
                }
                t6[a][0] = tr; t6[a][1] = ti;
            }
            float quad = 0.f, nr = 0.f, ni = 0.f;
#pragma unroll
            for (int a = 0; a < 6; ++a) {
                quad += wk[a][0] * t6[a][0] - wk[a][1] * t6[a][1];
                nr   += w6[a][0] * t6[a][0] - w6[a][1] * t6[a][1];
                ni   += w6[a][0] * t6[a][1] + w6[a][1] * t6[a][0];
            }
            float denom = fmaxf(quad, 1e-10f);
            float vkr, vki;
            if (m == kk) { vkr = 1.0f - 1.0f / sqrtf(denom); vki = 0.0f; }
            else { float inv = 1.0f / denom; vkr = nr * inv; vki = ni * inv; }
#pragma unroll
            for (int a = 0; a < 6; ++a) {
                w6[a][0] -= vkr * wk[a][0] - vki * wk[a][1];
                w6[a][1] -= vkr * wk[a][1] + vki * wk[a][0];
            }
        }
    }
    float d2 = 0.f, o2 = 0.f;
    if (act) {
        float* Wq = wNew + ((size_t)f * 36 + m * 6) * 2;
#pragma unroll
        for (int a = 0; a < 6; ++a) {
            Wq[2 * a] = w6[a][0]; Wq[2 * a + 1] = w6[a][1];
            float dr = w6[a][0] - wo6[a][0], di = w6[a][1] - wo6[a][1];
            d2 += dr * dr + di * di;
            o2 += wo6[a][0] * wo6[a][0] + wo6[a][1] * wo6[a][1];
        }
    }
#pragma unroll
    for (int d = 1; d < 8; d <<= 1) {
        d2 += __shfl_xor(d2, d);
        o2 += __shfl_xor(o2, d);
    }
    if (lane == 0) {
        atomicAdd(&flgOut[0], d2);
        atomicAdd(&flgOut[1], o2);
    }
}

// -------- pass A: r2 partials for 16 f's (W staged from global), atomic accumulate --------
// grid (16 tc, 33 fc), 256 threads.
__global__ __launch_bounds__(256) void passA(const float2* __restrict__ Xt,
                                             const float* __restrict__ Wcur,
                                             float* __restrict__ r2acc,
                                             const float* __restrict__ flgIn,
                                             int gate_en) {
    __shared__ float Wl[16][72];
    __shared__ float r2s[4][6][128];
    const int tid = threadIdx.x, wv = tid >> 6, lane = tid & 63;
    const int tc = blockIdx.x, fc = blockIdx.y;

    if (gate_en && flag_frozen(flgIn)) return;

    for (int idx = tid; idx < 16 * 72; idx += 256) {
        int fl = idx / 72, e = idx % 72;
        int ff = fc * 16 + fl;
        Wl[fl][e] = (ff < F_DIM) ? Wcur[(size_t)ff * 72 + e] : 0.f;
    }
    __syncthreads();

    const int t2 = tc * 128 + lane * 2;
    float acc[6][2];
#pragma unroll
    for (int k = 0; k < 6; ++k) { acc[k][0] = 0.f; acc[k][1] = 0.f; }
#pragma unroll
    for (int i = 0; i < 4; ++i) {
        const int ff = fc * 16 + wv * 4 + i;
        if (ff < F_DIM) {
            const float2* xf = Xt + (size_t)ff * 6 * T_DIM;
            float4 x4[6];
#pragma unroll
            for (int mm = 0; mm < 6; ++mm)
                x4[mm] = *(const float4*)(xf + (size_t)mm * T_DIM + t2);
            const float* wrow = Wl[wv * 4 + i];
#pragma unroll
            for (int k = 0; k < 6; ++k) {
                float y0r = 0.f, y0i = 0.f, y1r = 0.f, y1i = 0.f;
#pragma unroll
                for (int mm = 0; mm < 6; ++mm) {
                    float wr = wrow[(k * 6 + mm) * 2], wi = wrow[(k * 6 + mm) * 2 + 1];
                    y0r += wr * x4[mm].x - wi * x4[mm].y;
                    y0i += wr * x4[mm].y + wi * x4[mm].x;
                    y1r += wr * x4[mm].z - wi * x4[mm].w;
                    y1i += wr * x4[mm].w + wi * x4[mm].z;
                }
                acc[k][0] += y0r * y0r + y0i * y0i;
                acc[k][1] += y1r * y1r + y1i * y1i;
            }
        }
    }
#pragma unroll
    for (int k = 0; k < 6; ++k) {
        r2s[wv][k][lane * 2]     = acc[k][0];
        r2s[wv][k][lane * 2 + 1] = acc[k][1];
    }
    __syncthreads();
    for (int v = tid; v < 768; v += 256) {
        int k = v >> 7, l = v & 127;
        float s = r2s[0][k][l] + r2s[1][k][l] + r2s[2][k][l] + r2s[3][k][l];
        atomicAdd(&r2acc[k * T_DIM + tc * 128 + l], s);
    }
}

// -------- pass B (MFMA): V partials per (f, t-quarter); g inline from r2 --------
__global__ __launch_bounds__(384) void passB(const float2* __restrict__ Xt,
                                             float* __restrict__ ws,
                                             const float* __restrict__ flgIn,
                                             const float* __restrict__ r2in,
                                             float* __restrict__ r2zero,
                                             int gate_en) {
    __shared__ __align__(16) char plane[16 * 528];
    __shared__ __align__(16) float gbuf[6][256];
    const int tid = threadIdx.x, wv = tid >> 6, lane = tid & 63;
    const int f = blockIdx.x, tq = blockIdx.y;

    if (gate_en && flag_frozen(flgIn)) return;

    // zero a disjoint slice of the other-parity r2 accumulator
    {
        int bb = (f * 4 + tq) * 6;
#pragma unroll
        for (int i = 0; i < 6; ++i) {
            int idx = bb + i;
            if (idx < 12288) r2zero[idx] = 0.f;
        }
    }

    const float2* xb = Xt + (size_t)f * 6 * T_DIM;

    // zero rows 12..15 once (528 dwords)
    for (int i = tid; i < 528; i += 384) ((unsigned*)(plane + 12 * 528))[i] = 0;

    f32x4 acc0 = {0.f, 0.f, 0.f, 0.f};
    f32x4 acc1 = {0.f, 0.f, 0.f, 0.f};
    const int rc = lane & 15;
    const int G  = lane >> 4;
    const char* pu = plane + rc * 528 + G * 16;
    const float* gk = &gbuf[wv][0] + G * 8;

    for (int c = 0; c < 2; ++c) {
        const int t0 = tq * 512 + c * 256;
        __syncthreads();   // prior MFMA reads done before rewrite
        for (int i = tid; i < 1536; i += 384) {
            int kk = i >> 8, toff = i & 255;
            float s = r2in[kk * T_DIM + t0 + toff];
            float r = sqrtf(fmaxf(s, 1e-10f));
            gbuf[kk][toff] = 1.0f / fmaxf(r, 1e-10f);
        }
        for (int it = tid; it < 768; it += 384) {
            int mm = it >> 7, q = it & 127;
            float4 xv = *(const float4*)(xb + (size_t)mm * T_DIM + t0 + 2 * q);
            *(unsigned*)(plane + mm * 528 + 4 * q)       = pack2bf(xv.x, xv.z);
            *(unsigned*)(plane + (6 + mm) * 528 + 4 * q) = pack2bf(xv.y, xv.w);
        }
        __syncthreads();
#pragma unroll
        for (int s = 0; s < 8; ++s) {
            bf16x8 b = *(const bf16x8*)(pu + s * 64);
            f32x4 gA = *(const f32x4*)(gk + s * 32);
            f32x4 gB = *(const f32x4*)(gk + s * 32 + 4);
            const unsigned* bu = (const unsigned*)&b;
            bf16x8 a;
            unsigned* au = (unsigned*)&a;
            au[0] = pack2bf(__uint_as_float(bu[0] << 16) * gA[0],
                            __uint_as_float(bu[0] & 0xffff0000u) * gA[1]);
            au[1] = pack2bf(__uint_as_float(bu[1] << 16) * gA[2],
                            __uint_as_float(bu[1] & 0xffff0000u) * gA[3]);
            au[2] = pack2bf(__uint_as_float(bu[2] << 16) * gB[0],
                            __uint_as_float(bu[2] & 0xffff0000u) * gB[1]);
            au[3] = pack2bf(__uint_as_float(bu[3] << 16) * gB[2],
                            __uint_as_float(bu[3] & 0xffff0000u) * gB[3]);
            if (s & 1) acc1 = __builtin_amdgcn_mfma_f32_16x16x32_bf16(a, b, acc1, 0, 0, 0);
            else       acc0 = __builtin_amdgcn_mfma_f32_16x16x32_bf16(a, b, acc0, 0, 0, 0);
        }
    }
    __syncthreads();

    // dump S_k (16x16 f32) into LDS (reuse plane region)
    float* S = (float*)plane;
    {
        float* Sk = S + wv * 256;
#pragma unroll
        for (int r = 0; r < 4; ++r)
            Sk[(4 * G + r) * 16 + rc] = acc0[r] + acc1[r];   // D: row=4G+r, col=lane&15
    }
    __syncthreads();

    if (tid < 216) {
        const int kk = tid / 36, e = tid % 36;
        const float* Sk = S + kk * 256;
        float val;
        if (e < 6) {
            val = Sk[e * 16 + e] + Sk[(6 + e) * 16 + (6 + e)];
        } else if (e < 21) {
            int p = e - 6;
            int a = (p < 1) ? 1 : (p < 3) ? 2 : (p < 6) ? 3 : (p < 10) ? 4 : 5;
            int b = p - a * (a - 1) / 2;
            val = Sk[a * 16 + b] + Sk[(6 + a) * 16 + (6 + b)];
        } else {
            int p = e - 21;
            int a = (p < 1) ? 1 : (p < 3) ? 2 : (p < 6) ? 3 : (p < 10) ? 4 : 5;
            int b = p - a * (a - 1) / 2;
            val = Sk[(6 + a) * 16 + b] - Sk[a * 16 + (6 + b)];
        }
        ws[OFF_VP + ((size_t)f * 4 + tq) * 216 + tid] = val;
    }
}

// -------- final: out[k,t,f] = sum_m W[f,k,m] X[m,t,f], W cached in registers --------
__global__ __launch_bounds__(256) void finalY(const float2* __restrict__ X,
                                              const float* __restrict__ ws,
                                              float2* __restrict__ out) {
    const int f  = blockIdx.y * 256 + threadIdx.x;
    const int t0 = blockIdx.x * 4;
    if (f >= F_DIM) return;
    const float2* Wf = (const float2*)(ws + OFF_W0) + (size_t)f * 36;
    float2 w[36];
#pragma unroll
    for (int i = 0; i < 36; ++i) w[i] = Wf[i];
#pragma unroll
    for (int tl = 0; tl < 4; ++tl) {
        int t = t0 + tl;
        float2 x[6];
#pragma unroll
        for (int m = 0; m < 6; ++m) x[m] = X[((size_t)m * T_DIM + t) * F_DIM + f];
#pragma unroll
        for (int k = 0; k < 6; ++k) {
            float yr = 0.f, yi = 0.f;
#pragma unroll
            for (int m = 0; m < 6; ++m) {
                float2 wk = w[k * 6 + m];
                yr += wk.x * x[m].x - wk.y * x[m].y;
                yi += wk.x * x[m].y + wk.y * x[m].x;
            }
            out[((size_t)k * T_DIM + t) * F_DIM + f] = make_float2(yr, yi);
        }
    }
}

extern "C" void kernel_launch(void* const* d_in, const int* in_sizes, int n_in,
                              void* d_out, int out_size, void* d_ws, size_t ws_size,
                              hipStream_t stream) {
    (void)in_sizes; (void)n_in; (void)out_size; (void)ws_size;
    const float2* X = (const float2*)d_in[0];
    float* ws = (float*)d_ws;
    float2* out = (float2*)d_out;
    float2* Xt = out;  // transposed X lives in d_out until finalY overwrites it

    float* W[2]  = {ws + OFF_W0,  ws + OFF_W1};
    float* RA[2] = {ws + OFF_RA0, ws + OFF_RA1};
    float* FLG   = ws + OFF_FLG;   // FLG + 2*j = (d2,o2) sums for ISS(j); FLG+18 scratch

    transp<<<dim3(64, 17, 6), 256, 0, stream>>>(X, Xt, ws);
    for (int it = 0; it < N_ITER; ++it) {
        const float* wOld = (it == 0) ? W[0] : W[(it + 1) & 1];
        float* wNew = W[it & 1];
        if (it >= 1) {
            // ISS(it-1): gate on FLG[it-2], write FLG[it-1]
            const float* gIn = (it >= 2) ? FLG + 2 * (it - 2) : FLG;
            passI<<<F_DIM, 64, 0, stream>>>(ws, gIn, FLG + 2 * (it - 1),
                                            wOld, wNew, it >= 2);
        }
        // passA(it): r2 with W(it) = wNew; gate on FLG[it-1]
        const float* gA = (it >= 1) ? FLG + 2 * (it - 1) : FLG;
        passA<<<dim3(16, 33), 256, 0, stream>>>(Xt, wNew, RA[it & 1], gA, it >= 1);
        // passB(it): gate on FLG[it-1]
        passB<<<dim3(F_DIM, 4), 384, 0, stream>>>(Xt, ws, gA,
                                                  RA[it & 1], RA[(it + 1) & 1], it >= 1);
    }
    // final ISS(9): gate on FLG[8]; reads W1, writes W0; flag atomics to scratch FLG+18
    passI<<<F_DIM, 64, 0, stream>>>(ws, FLG + 16, FLG + 18, W[1], W[0], 1);
    finalY<<<dim3(T_DIM / 4, 3), 256, 0, stream>>>(X, ws, out);
}

// Round 16
// 574.296 us; speedup vs baseline: 1.1945x; 1.1665x over previous
//
#include <hip/hip_runtime.h>
#include <hip/hip_bf16.h>
#include <math.h>

#define T_DIM 2048
#define F_DIM 513
#define N_ITER 10

// ws float offsets
#define OFF_W0   0        // 513*36*2 = 36936 (W state, parity 0)
#define OFF_W1   36936    // 36936            (W state, parity 1)
#define OFF_FLG  73872    // 10 pairs (d2,o2) per-ISS-iteration convergence sums
#define OFF_RA0  73892    // 6*2048 r2 accumulator (parity 0)
#define OFF_RA1  86180    // 6*2048 r2 accumulator (parity 1)
#define OFF_VP   98468    // 513*4*216 V partials

typedef __attribute__((ext_vector_type(8))) short bf16x8;
typedef __attribute__((ext_vector_type(4))) float f32x4;

static __device__ inline unsigned pack2bf(float a, float b) {
    union { __hip_bfloat16 h; unsigned short u; } ca, cb;
    ca.h = __float2bfloat16(a);
    cb.h = __float2bfloat16(b);
    return (unsigned)ca.u | ((unsigned)cb.u << 16);
}

// helper: expand compact value index e (0..35) into complex 6x6 (V6 = 72 floats)
static __device__ inline void scatterV(float* V6, int e, float sum) {
    if (e < 6) {
        V6[(e * 6 + e) * 2]     = sum + 1e-6f;
        V6[(e * 6 + e) * 2 + 1] = 0.f;
    } else if (e < 21) {
        int p = e - 6;
        int a = (p < 1) ? 1 : (p < 3) ? 2 : (p < 6) ? 3 : (p < 10) ? 4 : 5;
        int b = p - a * (a - 1) / 2;
        V6[(a * 6 + b) * 2] = sum;
        V6[(b * 6 + a) * 2] = sum;
    } else {
        int p = e - 21;
        int a = (p < 1) ? 1 : (p < 3) ? 2 : (p < 6) ? 3 : (p < 10) ? 4 : 5;
        int b = p - a * (a - 1) / 2;
        V6[(a * 6 + b) * 2 + 1] =  sum;
        V6[(b * 6 + a) * 2 + 1] = -sum;
    }
}

static __device__ inline bool flag_frozen(const float* flg) {
    float rel = sqrtf(flg[0]) / fmaxf(sqrtf(flg[1]), 1.1920929e-07f);
    return rel < 1e-5f;
}

// -------- transpose X (K,T,F) -> Xt (F,K,T), + init W0=I, FLG=0, RA0=0 --------
__global__ __launch_bounds__(256) void transp(const float2* __restrict__ X,
                                              float2* __restrict__ Xt,
                                              float* __restrict__ ws) {
    const int fb  = blockIdx.x + 64 * (blockIdx.y + 17 * blockIdx.z);
    const int tid = threadIdx.x;
    if (fb < 73) {
        int idx = fb * 256 + tid;
        if (idx < F_DIM * 36) {
            int e = idx % 36;
            ws[OFF_W0 + 2 * idx]     = ((e / 6) == (e % 6)) ? 1.0f : 0.0f;
            ws[OFF_W0 + 2 * idx + 1] = 0.0f;
        }
    } else if (fb == 73) {
        if (tid < 20) ws[OFF_FLG + tid] = 0.0f;
    } else if (fb < 122) {
        int idx = (fb - 74) * 256 + tid;
        if (idx < 12288) ws[OFF_RA0 + idx] = 0.0f;
    }

    __shared__ float2 tile[32][33];
    const int k  = blockIdx.z;
    const int t0 = blockIdx.x * 32;
    const int f0 = blockIdx.y * 32;
    const int tx = tid & 31, ty = tid >> 5;
#pragma unroll
    for (int j = 0; j < 4; ++j) {
        int t = t0 + ty + j * 8;
        int f = f0 + tx;
        if (f < F_DIM) tile[ty + j * 8][tx] = X[((size_t)k * T_DIM + t) * F_DIM + f];
    }
    __syncthreads();
#pragma unroll
    for (int j = 0; j < 4; ++j) {
        int f = f0 + ty + j * 8;
        int t = t0 + tx;
        if (f < F_DIM) Xt[((size_t)f * 6 + k) * T_DIM + t] = tile[tx][ty + j * 8];
    }
}

// -------- pass A1C: ISS(it-1) for 16 f's, then r2 partials + atomic accumulate --------
// grid (16 tc, 33 fc), 256 threads.
__global__ __launch_bounds__(256) void passA1C(const float2* __restrict__ Xt,
                                               float* __restrict__ ws,
                                               const float* __restrict__ flgIn,
                                               float* __restrict__ flgOut,
                                               const float* __restrict__ wOld,
                                               float* __restrict__ wNew,
                                               float* __restrict__ r2acc,
                                               int do_iss, int gate_en) {
    __shared__ float Wl[16][72];     // W rows (complex) per local f
    __shared__ float VL[16][432];    // V complex per local f; reused as r2s in body
    const int tid = threadIdx.x, wv = tid >> 6, lane = tid & 63;
    const int tc = blockIdx.x, fc = blockIdx.y;

    const bool frozen = gate_en ? flag_frozen(flgIn) : false;

    const int fl = wv * 4 + (lane >> 4);   // local f 0..15
    const int f  = fc * 16 + fl;
    const int m  = lane & 15;              // row index (active if <6)
    const bool act = (f < F_DIM) && (m < 6);

    if (do_iss == 0) {
        if (act) {
            const float* Wp = wOld + ((size_t)f * 36 + m * 6) * 2;
#pragma unroll
            for (int a = 0; a < 6; ++a) {
                Wl[fl][(m * 6 + a) * 2]     = Wp[2 * a];
                Wl[fl][(m * 6 + a) * 2 + 1] = Wp[2 * a + 1];
            }
        }
    } else if (frozen) {
        if (act) {
            const float* Wp = wOld + ((size_t)f * 36 + m * 6) * 2;
            float* Wq = wNew + ((size_t)f * 36 + m * 6) * 2;
#pragma unroll
            for (int a = 0; a < 6; ++a) {
                Wq[2 * a] = Wp[2 * a]; Wq[2 * a + 1] = Wp[2 * a + 1];
            }
        }
        if (tc == 0 && m == 0 && f < F_DIM) atomicAdd(&flgOut[1], 1.0f);
    } else {
        // build V (sum 4 VP partials) into VL[fl]
        if (f < F_DIM) {
            const float* vp = ws + OFF_VP + (size_t)f * 4 * 216;
            for (int v = m; v < 216; v += 16) {
                float sum = (vp[v] + vp[216 + v] + vp[432 + v] + vp[648 + v]) * (1.0f / (float)T_DIM);
                scatterV(&VL[fl][(v / 36) * 72], v % 36, sum);
            }
        }
        __syncthreads();
        float w6[6][2], wo6[6][2];
#pragma unroll
        for (int a = 0; a < 6; ++a) { w6[a][0] = 0.f; w6[a][1] = 0.f; wo6[a][0] = 0.f; wo6[a][1] = 0.f; }
        if (act) {
            const float* Wp = wOld + ((size_t)f * 36 + m * 6) * 2;
#pragma unroll
            for (int a = 0; a < 6; ++a) {
                w6[a][0] = Wp[2 * a]; w6[a][1] = Wp[2 * a + 1];
                wo6[a][0] = w6[a][0]; wo6[a][1] = w6[a][1];
            }
        }
        const float2* Vm = (const float2*)&VL[fl][0];
        for (int kk = 0; kk < 6; ++kk) {
            float wk[6][2];
#pragma unroll
            for (int a = 0; a < 6; ++a) {
                wk[a][0] = __shfl(w6[a][0], kk, 16);
                wk[a][1] = __shfl(w6[a][1], kk, 16);
            }
            if (act) {
                float t6[6][2];
#pragma unroll
                for (int a = 0; a < 6; ++a) {
                    float tr = 0.f, ti = 0.f;
#pragma unroll
                    for (int b = 0; b < 6; ++b) {
                        float2 vv = Vm[m * 36 + a * 6 + b];
                        tr += vv.x * wk[b][0] + vv.y * wk[b][1];
                        ti += vv.y * wk[b][0] - vv.x * wk[b][1];
                    }
                    t6[a][0] = tr; t6[a][1] = ti;
                }
                float quad = 0.f, nr = 0.f, ni = 0.f;
#pragma unroll
                for (int a = 0; a < 6; ++a) {
                    quad += wk[a][0] * t6[a][0] - wk[a][1] * t6[a][1];
                    nr   += w6[a][0] * t6[a][0] - w6[a][1] * t6[a][1];
                    ni   += w6[a][0] * t6[a][1] + w6[a][1] * t6[a][0];
                }
                float denom = fmaxf(quad, 1e-10f);
                float vkr, vki;
                if (m == kk) { vkr = 1.0f - 1.0f / sqrtf(denom); vki = 0.0f; }
                else { float inv = 1.0f / denom; vkr = nr * inv; vki = ni * inv; }
#pragma unroll
                for (int a = 0; a < 6; ++a) {
                    w6[a][0] -= vkr * wk[a][0] - vki * wk[a][1];
                    w6[a][1] -= vkr * wk[a][1] + vki * wk[a][0];
                }
            }
        }
        float d2 = 0.f, o2 = 0.f;
        if (act) {
            float* Wq = wNew + ((size_t)f * 36 + m * 6) * 2;
#pragma unroll
            for (int a = 0; a < 6; ++a) {
                Wq[2 * a] = w6[a][0]; Wq[2 * a + 1] = w6[a][1];
                Wl[fl][(m * 6 + a) * 2] = w6[a][0]; Wl[fl][(m * 6 + a) * 2 + 1] = w6[a][1];
                float dr = w6[a][0] - wo6[a][0], di = w6[a][1] - wo6[a][1];
                d2 += dr * dr + di * di;
                o2 += wo6[a][0] * wo6[a][0] + wo6[a][1] * wo6[a][1];
            }
        }
#pragma unroll
        for (int d = 1; d < 8; d <<= 1) {
            d2 += __shfl_xor(d2, d);
            o2 += __shfl_xor(o2, d);
        }
        if (tc == 0 && m == 0 && f < F_DIM) {
            atomicAdd(&flgOut[0], d2);
            atomicAdd(&flgOut[1], o2);
        }
    }
    __syncthreads();
    if (do_iss && frozen) return;

    // ---- body: r2 partials for the same 16 f's, atomic accumulate ----
    float* r2s = &VL[0][0];   // [4 wv][6 k][128 t] = 3072 floats (reuse VL)
    const int t2 = tc * 128 + lane * 2;
    float acc[6][2];
#pragma unroll
    for (int k = 0; k < 6; ++k) { acc[k][0] = 0.f; acc[k][1] = 0.f; }
#pragma unroll
    for (int i = 0; i < 4; ++i) {
        const int ff = fc * 16 + wv * 4 + i;
        if (ff < F_DIM) {
            const float2* xf = Xt + (size_t)ff * 6 * T_DIM;
            float4 x4[6];
#pragma unroll
            for (int mm = 0; mm < 6; ++mm)
                x4[mm] = *(const float4*)(xf + (size_t)mm * T_DIM + t2);
            const float* wrow = Wl[wv * 4 + i];
#pragma unroll
            for (int k = 0; k < 6; ++k) {
                float y0r = 0.f, y0i = 0.f, y1r = 0.f, y1i = 0.f;
#pragma unroll
                for (int mm = 0; mm < 6; ++mm) {
                    float wr = wrow[(k * 6 + mm) * 2], wi = wrow[(k * 6 + mm) * 2 + 1];
                    y0r += wr * x4[mm].x - wi * x4[mm].y;
                    y0i += wr * x4[mm].y + wi * x4[mm].x;
                    y1r += wr * x4[mm].z - wi * x4[mm].w;
                    y1i += wr * x4[mm].w + wi * x4[mm].z;
                }
                acc[k][0] += y0r * y0r + y0i * y0i;
                acc[k][1] += y1r * y1r + y1i * y1i;
            }
        }
    }
    __syncthreads();   // done reading VL-as-V before overwriting as r2s
#pragma unroll
    for (int k = 0; k < 6; ++k) {
        r2s[(wv * 6 + k) * 128 + lane * 2]     = acc[k][0];
        r2s[(wv * 6 + k) * 128 + lane * 2 + 1] = acc[k][1];
    }
    __syncthreads();
    for (int v = tid; v < 768; v += 256) {
        int k = v >> 7, l = v & 127;
        float s = r2s[(0 * 6 + k) * 128 + l] + r2s[(1 * 6 + k) * 128 + l]
                + r2s[(2 * 6 + k) * 128 + l] + r2s[(3 * 6 + k) * 128 + l];
        atomicAdd(&r2acc[k * T_DIM + tc * 128 + l], s);
    }
}

// -------- pass B (MFMA): V partials per (f, t-quarter); g inline from r2 --------
__global__ __launch_bounds__(384) void passB(const float2* __restrict__ Xt,
                                             float* __restrict__ ws,
                                             const float* __restrict__ flgIn,
                                             const float* __restrict__ r2in,
                                             float* __restrict__ r2zero,
                                             int gate_en) {
    __shared__ __align__(16) char plane[16 * 528];
    __shared__ __align__(16) float gbuf[6][256];
    const int tid = threadIdx.x, wv = tid >> 6, lane = tid & 63;
    const int f = blockIdx.x, tq = blockIdx.y;

    if (gate_en && flag_frozen(flgIn)) return;

    // zero a disjoint slice of the other-parity r2 accumulator
    {
        int bb = (f * 4 + tq) * 6;
#pragma unroll
        for (int i = 0; i < 6; ++i) {
            int idx = bb + i;
            if (idx < 12288) r2zero[idx] = 0.f;
        }
    }

    const float2* xb = Xt + (size_t)f * 6 * T_DIM;

    // zero rows 12..15 once (528 dwords)
    for (int i = tid; i < 528; i += 384) ((unsigned*)(plane + 12 * 528))[i] = 0;

    f32x4 acc0 = {0.f, 0.f, 0.f, 0.f};
    f32x4 acc1 = {0.f, 0.f, 0.f, 0.f};
    const int rc = lane & 15;
    const int G  = lane >> 4;
    const char* pu = plane + rc * 528 + G * 16;
    const float* gk = &gbuf[wv][0] + G * 8;

    for (int c = 0; c < 2; ++c) {
        const int t0 = tq * 512 + c * 256;
        __syncthreads();   // prior MFMA reads done before rewrite
        for (int i = tid; i < 1536; i += 384) {
            int kk = i >> 8, toff = i & 255;
            float s = r2in[kk * T_DIM + t0 + toff];
            float r = sqrtf(fmaxf(s, 1e-10f));
            gbuf[kk][toff] = 1.0f / fmaxf(r, 1e-10f);
        }
        for (int it = tid; it < 768; it += 384) {
            int mm = it >> 7, q = it & 127;
            float4 xv = *(const float4*)(xb + (size_t)mm * T_DIM + t0 + 2 * q);
            *(unsigned*)(plane + mm * 528 + 4 * q)       = pack2bf(xv.x, xv.z);
            *(unsigned*)(plane + (6 + mm) * 528 + 4 * q) = pack2bf(xv.y, xv.w);
        }
        __syncthreads();
#pragma unroll
        for (int s = 0; s < 8; ++s) {
            bf16x8 b = *(const bf16x8*)(pu + s * 64);
            f32x4 gA = *(const f32x4*)(gk + s * 32);
            f32x4 gB = *(const f32x4*)(gk + s * 32 + 4);
            const unsigned* bu = (const unsigned*)&b;
            bf16x8 a;
            unsigned* au = (unsigned*)&a;
            au[0] = pack2bf(__uint_as_float(bu[0] << 16) * gA[0],
                            __uint_as_float(bu[0] & 0xffff0000u) * gA[1]);
            au[1] = pack2bf(__uint_as_float(bu[1] << 16) * gA[2],
                            __uint_as_float(bu[1] & 0xffff0000u) * gA[3]);
            au[2] = pack2bf(__uint_as_float(bu[2] << 16) * gB[0],
                            __uint_as_float(bu[2] & 0xffff0000u) * gB[1]);
            au[3] = pack2bf(__uint_as_float(bu[3] << 16) * gB[2],
                            __uint_as_float(bu[3] & 0xffff0000u) * gB[3]);
            if (s & 1) acc1 = __builtin_amdgcn_mfma_f32_16x16x32_bf16(a, b, acc1, 0, 0, 0);
            else       acc0 = __builtin_amdgcn_mfma_f32_16x16x32_bf16(a, b, acc0, 0, 0, 0);
        }
    }
    __syncthreads();

    // dump S_k (16x16 f32) into LDS (reuse plane region)
    float* S = (float*)plane;
    {
        float* Sk = S + wv * 256;
#pragma unroll
        for (int r = 0; r < 4; ++r)
            Sk[(4 * G + r) * 16 + rc] = acc0[r] + acc1[r];   // D: row=4G+r, col=lane&15
    }
    __syncthreads();

    if (tid < 216) {
        const int kk = tid / 36, e = tid % 36;
        const float* Sk = S + kk * 256;
        float val;
        if (e < 6) {
            val = Sk[e * 16 + e] + Sk[(6 + e) * 16 + (6 + e)];
        } else if (e < 21) {
            int p = e - 6;
            int a = (p < 1) ? 1 : (p < 3) ? 2 : (p < 6) ? 3 : (p < 10) ? 4 : 5;
            int b = p - a * (a - 1) / 2;
            val = Sk[a * 16 + b] + Sk[(6 + a) * 16 + (6 + b)];
        } else {
            int p = e - 21;
            int a = (p < 1) ? 1 : (p < 3) ? 2 : (p < 6) ? 3 : (p < 10) ? 4 : 5;
            int b = p - a * (a - 1) / 2;
            val = Sk[(6 + a) * 16 + b] - Sk[a * 16 + (6 + b)];
        }
        ws[OFF_VP + ((size_t)f * 4 + tq) * 216 + tid] = val;
    }
}

// -------- pass C (final ISS only) --------
__global__ __launch_bounds__(64) void passC(float* __restrict__ ws,
                                            const float* __restrict__ flgIn,
                                            const float* __restrict__ wOld,
                                            float* __restrict__ wNew) {
    __shared__ float VL[432];
    const int f = blockIdx.x;
    const int lane = threadIdx.x;
    if (flag_frozen(flgIn)) {
        for (int v = lane; v < 72; v += 64)
            wNew[(size_t)f * 72 + v] = wOld[(size_t)f * 72 + v];
        return;
    }
    {
        const float* vp = ws + OFF_VP + (size_t)f * 4 * 216;
        for (int v = lane; v < 216; v += 64) {
            float sum = (vp[v] + vp[216 + v] + vp[432 + v] + vp[648 + v]) * (1.0f / (float)T_DIM);
            scatterV(&VL[(v / 36) * 72], v % 36, sum);
        }
    }
    __syncthreads();

    const int m = lane;
    const bool act = (m < 6);
    float w6[6][2];
#pragma unroll
    for (int a = 0; a < 6; ++a) { w6[a][0] = 0.f; w6[a][1] = 0.f; }
    if (act) {
        const float* Wp = wOld + ((size_t)f * 36 + m * 6) * 2;
#pragma unroll
        for (int a = 0; a < 6; ++a) {
            w6[a][0] = Wp[2 * a]; w6[a][1] = Wp[2 * a + 1];
        }
    }
    const float2* Vm = (const float2*)VL;
    for (int kk = 0; kk < 6; ++kk) {
        float wk[6][2];
#pragma unroll
        for (int a = 0; a < 6; ++a) {
            wk[a][0] = __shfl(w6[a][0], kk);
            wk[a][1] = __shfl(w6[a][1], kk);
        }
        if (act) {
            float t6[6][2];
#pragma unroll
            for (int a = 0; a < 6; ++a) {
                float tr = 0.f, ti = 0.f;
#pragma unroll
                for (int b = 0; b < 6; ++b) {
                    float2 vv = Vm[m * 36 + a * 6 + b];
                    tr += vv.x * wk[b][0] + vv.y * wk[b][1];
                    ti += vv.y * wk[b][0] - vv.x * wk[b][1];
                }
                t6[a][0] = tr; t6[a][1] = ti;
            }
            float quad = 0.f, nr = 0.f, ni = 0.f;
#pragma unroll
            for (int a = 0; a < 6; ++a) {
                quad += wk[a][0] * t6[a][0] - wk[a][1] * t6[a][1];
                nr   += w6[a][0] * t6[a][0] - w6[a][1] * t6[a][1];
                ni   += w6[a][0] * t6[a][1] + w6[a][1] * t6[a][0];
            }
            float denom = fmaxf(quad, 1e-10f);
            float vkr, vki;
            if (m == kk) { vkr = 1.0f - 1.0f / sqrtf(denom); vki = 0.0f; }
            else { float inv = 1.0f / denom; vkr = nr * inv; vki = ni * inv; }
#pragma unroll
            for (int a = 0; a < 6; ++a) {
                w6[a][0] -= vkr * wk[a][0] - vki * wk[a][1];
                w6[a][1] -= vkr * wk[a][1] + vki * wk[a][0];
            }
        }
    }
    if (act) {
        float* Wq = wNew + ((size_t)f * 36 + m * 6) * 2;
#pragma unroll
        for (int a = 0; a < 6; ++a) {
            Wq[2 * a] = w6[a][0]; Wq[2 * a + 1] = w6[a][1];
        }
    }
}

// -------- final: out[k,t,f] = sum_m W[f,k,m] X[m,t,f], W cached in registers --------
__global__ __launch_bounds__(256) void finalY(const float2* __restrict__ X,
                                              const float* __restrict__ ws,
                                              float2* __restrict__ out) {
    const int f  = blockIdx.y * 256 + threadIdx.x;
    const int t0 = blockIdx.x * 8;
    if (f >= F_DIM) return;
    const float2* Wf = (const float2*)(ws + OFF_W0) + (size_t)f * 36;
    float2 w[36];
#pragma unroll
    for (int i = 0; i < 36; ++i) w[i] = Wf[i];
#pragma unroll
    for (int tl = 0; tl < 8; ++tl) {
        int t = t0 + tl;
        float2 x[6];
#pragma unroll
        for (int m = 0; m < 6; ++m) x[m] = X[((size_t)m * T_DIM + t) * F_DIM + f];
#pragma unroll
        for (int k = 0; k < 6; ++k) {
            float yr = 0.f, yi = 0.f;
#pragma unroll
            for (int m = 0; m < 6; ++m) {
                float2 wk = w[k * 6 + m];
                yr += wk.x * x[m].x - wk.y * x[m].y;
                yi += wk.x * x[m].y + wk.y * x[m].x;
            }
            out[((size_t)k * T_DIM + t) * F_DIM + f] = make_float2(yr, yi);
        }
    }
}

extern "C" void kernel_launch(void* const* d_in, const int* in_sizes, int n_in,
                              void* d_out, int out_size, void* d_ws, size_t ws_size,
                              hipStream_t stream) {
    (void)in_sizes; (void)n_in; (void)out_size; (void)ws_size;
    const float2* X = (const float2*)d_in[0];
    float* ws = (float*)d_ws;
    float2* out = (float2*)d_out;
    float2* Xt = out;  // transposed X lives in d_out until finalY overwrites it

    float* W[2]  = {ws + OFF_W0,  ws + OFF_W1};
    float* RA[2] = {ws + OFF_RA0, ws + OFF_RA1};
    float* FLG   = ws + OFF_FLG;   // FLG + 2*j = (d2,o2) sums for ISS(j)

    transp<<<dim3(64, 17, 6), 256, 0, stream>>>(X, Xt, ws);
    for (int it = 0; it < N_ITER; ++it) {
        const float* wOld = (it == 0) ? W[0] : W[(it + 1) & 1];
        float* wNew = W[it & 1];
        // A1C(it) hosts ISS(it-1): gate on FLG[it-2], write FLG[it-1]
        const float* gIn = (it >= 2) ? FLG + 2 * (it - 2) : FLG;
        float* gOut      = (it >= 1) ? FLG + 2 * (it - 1) : FLG + 18;
        passA1C<<<dim3(16, 33), 256, 0, stream>>>(Xt, ws, gIn, gOut, wOld, wNew,
                                                  RA[it & 1], it > 0, it >= 2);
        // passB(it): gate on FLG[it-1]
        const float* gB = (it >= 1) ? FLG + 2 * (it - 1) : FLG;
        passB<<<dim3(F_DIM, 4), 384, 0, stream>>>(Xt, ws, gB,
                                                  RA[it & 1], RA[(it + 1) & 1], it >= 1);
    }
    // final ISS(9): gate on FLG[8]; reads W1, writes W0
    passC<<<F_DIM, 64, 0, stream>>>(ws, FLG + 16, W[1], W[0]);
    finalY<<<dim3(T_DIM / 8, 3), 256, 0, stream>>>(X, ws, out);
}